// Round 13
// baseline (187.261 us; speedup 1.0000x reference)
//
#include <hip/hip_runtime.h>

#define Bq 4
#define Cc 2048
#define Ss 1024
#define Hh 16
#define Dd 128

// 1/sqrt(128) * log2(e): softmax runs in exp2 domain, folded into Q at load
#define QSCALE 0.127517429f

typedef __bf16 bf16x8 __attribute__((ext_vector_type(8)));
typedef float  f32x4  __attribute__((ext_vector_type(4)));

__device__ __forceinline__ ushort f2bf(float f) {
    uint u = __float_as_uint(f);
    u += 0x7FFFu + ((u >> 16) & 1u);   // RNE
    return (ushort)(u >> 16);
}
__device__ __forceinline__ uint pack2bf(float a, float b) {
    return (uint)f2bf(a) | ((uint)f2bf(b) << 16);
}
__device__ __forceinline__ void gld16(const void* g, void* l) {
    __builtin_amdgcn_global_load_lds(
        (const __attribute__((address_space(1))) unsigned int*)g,
        (__attribute__((address_space(3))) unsigned int*)l, 16, 0, 0);
}

// ---------------------------------------------------------------------------
// prep_all3: one kernel, four block-ranges (Q handled inside attn).
//   [0,2048)     W fp32[2048][2048] -> bf16, intra-128B XOR swizzle (row&7)
//                (swizzle kept: proj5 stages W into LDS and XOR-reads it)
//   [2048,6144)  V fp32 -> bf16, k-permuted (swapped-QK P layout), LINEAR
//                (no row-XOR: attn now reads V straight from L1/L2)
//   [6144,7168)  K transpose [d][S] -> [S][128] bf16, LINEAR (no XOR)
//   [7168]       mask -> bias (0/-1e30), runtime dtype detection
// ---------------------------------------------------------------------------
__global__ __launch_bounds__(256) void prep_all3(const float* __restrict__ w,
                                                 const float* __restrict__ v,
                                                 const float* __restrict__ keys,
                                                 const unsigned* __restrict__ mask,
                                                 ushort* __restrict__ wb,
                                                 ushort* __restrict__ vb,
                                                 ushort* __restrict__ Kt,
                                                 float* __restrict__ bias) {
    __shared__ __align__(16) float T[128][65];
    const int t = threadIdx.x;
    const int blk = blockIdx.x;

    if (blk < 2048) {
        // ---- W convert+swizzle ----
        const size_t e = ((size_t)blk * 256 + t) * 8;
        const int row = (int)(e >> 11), col = (int)(e & 2047);
        const int colS = (col & ~63) | ((col & 63) ^ ((row & 7) << 3));
        float4 v0 = *(const float4*)&w[e];
        float4 v1 = *(const float4*)&w[e + 4];
        uint4 o;
        o.x = pack2bf(v0.x, v0.y); o.y = pack2bf(v0.z, v0.w);
        o.z = pack2bf(v1.x, v1.y); o.w = pack2bf(v1.z, v1.w);
        *(uint4*)&wb[(size_t)row * 2048 + colS] = o;
    } else if (blk < 6144) {
        // ---- V convert + k-permute (linear placement) ----
        const int tid = (blk - 2048) * 256 + t;    // 0 .. 1M-1
        const int row = tid >> 7;                   // 0..8191
        const int cp = tid & 127;
        const int blk64 = (cp >> 3) * 64;
        const int j0 = cp & 7;
        const int b5 = j0 >> 2, h = j0 & 3;
        const float* src = v + (size_t)row * 1024 + blk64 + 32 * b5 + 4 * h;
        float4 A = *(const float4*)src;
        float4 B = *(const float4*)(src + 16);
        uint4 o;
        o.x = pack2bf(A.x, A.y); o.y = pack2bf(A.z, A.w);
        o.z = pack2bf(B.x, B.y); o.w = pack2bf(B.z, B.w);
        *(uint4*)&vb[(size_t)row * 1024 + blk64 + j0 * 8] = o;
    } else if (blk < 7168) {
        // ---- K transpose+convert (linear placement) ----
        const int b2 = blk - 6144;
        const int s0 = (b2 & 15) * 64;
        const int bh = b2 >> 4;
        const float* src = keys + (size_t)bh * 128 * 1024;
#pragma unroll
        for (int p = 0; p < 8; ++p) {
            const int d = p * 16 + (t >> 4);
            float4 v4 = *(const float4*)&src[(size_t)d * 1024 + s0 + (t & 15) * 4];
            T[d][(t & 15) * 4 + 0] = v4.x;
            T[d][(t & 15) * 4 + 1] = v4.y;
            T[d][(t & 15) * 4 + 2] = v4.z;
            T[d][(t & 15) * 4 + 3] = v4.w;
        }
        __syncthreads();
#pragma unroll
        for (int p = 0; p < 4; ++p) {
            const int k = p * 16 + (t >> 4);
            const int x = t & 15;
            uint4 o;
            o.x = pack2bf(T[x * 8 + 0][k], T[x * 8 + 1][k]);
            o.y = pack2bf(T[x * 8 + 2][k], T[x * 8 + 3][k]);
            o.z = pack2bf(T[x * 8 + 4][k], T[x * 8 + 5][k]);
            o.w = pack2bf(T[x * 8 + 6][k], T[x * 8 + 7][k]);
            const size_t rowbyte = ((size_t)bh * 1024 + s0 + k) * 256;
            *(uint4*)((char*)Kt + rowbyte + x * 16) = o;
        }
    } else {
        // ---- mask -> bias ----
        __shared__ int f01, ff;
        if (t == 0) { f01 = 0; ff = 0; }
        __syncthreads();
        int a = 0, c = 0;
        for (int i = t; i < 1024; i += 256) {
            unsigned vv = mask[i];
            if (vv != 0u && vv != 1u) a = 1;
            if (vv != 0u && vv != 0x3F800000u) c = 1;
        }
        if (a) atomicOr(&f01, 1);
        if (c) atomicOr(&ff, 1);
        __syncthreads();
        const int mode = f01 ? (ff ? 1 : 2) : 0;
        const int* mi = (const int*)mask;
        const unsigned char* mb = (const unsigned char*)mask;
        const float* mf = (const float*)mask;
        for (int i = t; i < Bq * Ss; i += 256) {
            bool on;
            if (mode == 0)      on = (mi[i] != 0);
            else if (mode == 1) on = (mb[i] != 0);
            else                on = (mf[i] != 0.0f);
            bias[i] = on ? 0.0f : -1e30f;
        }
    }
}

// ---------------------------------------------------------------------------
// MFMA flash attention v12 — BARRIER-FREE main loop. 512 blocks x 256 thr
// (4 waves); q-tile 128 (wave owns 32 q). K/V fragments loaded DIRECTLY from
// global (Kt/Vbf are L1/L2-resident: 16KB K-tile + 16KB V-tile per chunk,
// XCD-affine bh placement). No LDS staging, no barriers, no vmcnt coupling
// in the main loop -> waves free-run at different phases; with 36KB LDS and
// moderate VGPR, 3-4 blocks/CU co-resident overlap MFMA/VALU/load pipes.
// Swapped-QK, P in registers, bias as MFMA C-init. Q built in a short LDS
// prologue (hidden by other blocks' main loops).
// ---------------------------------------------------------------------------
__global__ __launch_bounds__(256) void attn12(const float* __restrict__ queries,
                                              const ushort* __restrict__ Kt,
                                              const ushort* __restrict__ Vbf,
                                              const float* __restrict__ bias,
                                              ushort* __restrict__ hidT) {
    __shared__ __align__(16) char SMEM[36864];
    // [0,32768): Q fp32 stage [64 d][128 q] per half; later hid stage [128][256B]
    // [32768,36864): biasS
    float* biasS = (float*)(SMEM + 32768);

    const int t = threadIdx.x, l = t & 63, w = t >> 6;   // w = 0..3
    const int kk = l & 15, g = l >> 4;

    const int bid = blockIdx.x;
    const int vid = (bid & 7) * 64 + (bid >> 3);   // 512 blocks, XCD-bijective
    const int bh = vid >> 3, qt = vid & 7;
    const int b = bh >> 4, hh = bh & 15;
    const int q0 = qt * 128;

    for (int i = t; i < Ss; i += 256) biasS[i] = bias[b * Ss + i];

    // ---- Q prologue: stage [64 d][128 q] fp32 per half, extract fragments ----
    bf16x8 qf[2][4];
    {
        const float* Qg = queries + (size_t)(b * Cc + hh * Dd) * Ss;
        float* Qstg = (float*)SMEM;
#pragma unroll
        for (int half = 0; half < 2; ++half) {
#pragma unroll
            for (int it = 0; it < 8; ++it) {
                const int i2 = it * 4 + w;          // 0..31; covers rows 2i2,2i2+1
                gld16(Qg + (size_t)(half * 64 + 2 * i2 + (l >> 5)) * 1024 +
                          q0 + (l & 31) * 4,
                      (char*)Qstg + i2 * 1024);
            }
            asm volatile("s_waitcnt vmcnt(0)" ::: "memory");
            __syncthreads();
#pragma unroll
            for (int dch = 0; dch < 2; ++dch) {
                const int dc = half * 2 + dch;
#pragma unroll
                for (int qs = 0; qs < 2; ++qs) {
                    const int q = w * 32 + qs * 16 + kk;
                    float f[8];
#pragma unroll
                    for (int j = 0; j < 8; ++j) {
                        const int dl = dch * 32 + g * 8 + j;   // 0..63
                        f[j] = Qstg[dl * 128 + q];
                    }
                    uint4 u;
                    u.x = pack2bf(f[0] * QSCALE, f[1] * QSCALE);
                    u.y = pack2bf(f[2] * QSCALE, f[3] * QSCALE);
                    u.z = pack2bf(f[4] * QSCALE, f[5] * QSCALE);
                    u.w = pack2bf(f[6] * QSCALE, f[7] * QSCALE);
                    qf[qs][dc] = *(bf16x8*)&u;
                }
            }
            __syncthreads();   // extraction done before next-half overwrite
        }
    }

    float lrun[2] = {0.0f, 0.0f};
    f32x4 hacc[2][8];
#pragma unroll
    for (int qs = 0; qs < 2; ++qs)
#pragma unroll
        for (int i = 0; i < 8; ++i) hacc[qs][i] = (f32x4){0.f, 0.f, 0.f, 0.f};

    const ushort* Kbh = Kt + (size_t)bh * 1024 * 128;
    const ushort* Vbh = Vbf + (size_t)bh * 128 * 1024;

    // ---- main loop: NO barriers, NO LDS; K/V straight from L1/L2 ----
#pragma unroll 1
    for (int ck = 0; ck < 16; ++ck) {
        const int k0 = ck * 64;

        // QK^T swapped: A = K rows (global), B = Q regs; C-init = bias
        f32x4 sc[2][4];
        __builtin_amdgcn_s_setprio(1);
#pragma unroll
        for (int ns = 0; ns < 4; ++ns) {
            const f32x4 ci = *(const f32x4*)&biasS[k0 + ns * 16 + g * 4];
            const ushort* kr = Kbh + (size_t)(k0 + ns * 16 + kk) * 128;
            bf16x8 kf[4];
#pragma unroll
            for (int dc = 0; dc < 4; ++dc)
                kf[dc] = *(const bf16x8*)(kr + dc * 32 + g * 8);
#pragma unroll
            for (int qs = 0; qs < 2; ++qs) {
                f32x4 a = ci;
#pragma unroll
                for (int dc = 0; dc < 4; ++dc)
                    a = __builtin_amdgcn_mfma_f32_16x16x32_bf16(
                        kf[dc], qf[qs][dc], a, 0, 0, 0);
                sc[qs][ns] = a;
            }
        }
        __builtin_amdgcn_s_setprio(0);

        // fixed-max softmax in registers
        bf16x8 pb[2][2];
#pragma unroll
        for (int qs = 0; qs < 2; ++qs) {
            float pv[4][4];
            float s = 0.0f;
#pragma unroll
            for (int ns = 0; ns < 4; ++ns)
#pragma unroll
                for (int r = 0; r < 4; ++r) {
                    float p = exp2f(sc[qs][ns][r]);
                    pv[ns][r] = p;
                    s += p;
                }
            lrun[qs] += s;
#pragma unroll
            for (int kh = 0; kh < 2; ++kh) {
                bf16x8 vpk;
#pragma unroll
                for (int j = 0; j < 8; ++j)
                    vpk[j] = (__bf16)pv[2 * kh + (j >> 2)][j & 3];
                pb[qs][kh] = vpk;
            }
        }

        // PV: V rows straight from global (k-permuted layout matches pb)
        __builtin_amdgcn_s_setprio(1);
#pragma unroll
        for (int kh = 0; kh < 2; ++kh) {
#pragma unroll
            for (int ds = 0; ds < 8; ++ds) {
                bf16x8 vf = *(const bf16x8*)(Vbh + (size_t)(ds * 16 + kk) * 1024 +
                                             k0 + kh * 32 + g * 8);
                hacc[0][ds] = __builtin_amdgcn_mfma_f32_16x16x32_bf16(
                    vf, pb[0][kh], hacc[0][ds], 0, 0, 0);
                hacc[1][ds] = __builtin_amdgcn_mfma_f32_16x16x32_bf16(
                    vf, pb[1][kh], hacc[1][ds], 0, 0, 0);
            }
        }
        __builtin_amdgcn_s_setprio(0);
    }

    // l reduction across the 4 g-groups
    float linv[2];
#pragma unroll
    for (int qs = 0; qs < 2; ++qs) {
        float s = lrun[qs];
        s += __shfl_xor(s, 16);
        s += __shfl_xor(s, 32);
        linv[qs] = 1.0f / s;
    }

    __syncthreads();   // all waves past biasS/Qstg use; reuse SMEM as hid stage
    {
        ushort* hs = (ushort*)SMEM;
#pragma unroll
        for (int qs = 0; qs < 2; ++qs) {
            const int row = w * 32 + qs * 16 + kk;     // 0..127
#pragma unroll
            for (int ds = 0; ds < 8; ++ds) {
                uint2 pk;
                pk.x = pack2bf(hacc[qs][ds][0] * linv[qs], hacc[qs][ds][1] * linv[qs]);
                pk.y = pack2bf(hacc[qs][ds][2] * linv[qs], hacc[qs][ds][3] * linv[qs]);
                const int off = row * 256 + ((ds * 32 + g * 8) ^ ((row & 7) << 4));
                *(uint2*)((char*)hs + off) = pk;
            }
        }
    }
    __syncthreads();

    const char* hsb = (const char*)SMEM;
#pragma unroll
    for (int it = 0; it < 8; ++it) {
        const int idx = it * 256 + t;                  // 0..2047
        const int q = idx >> 4, x = idx & 15;
        uint4 vv = *(const uint4*)(hsb + q * 256 + x * 16);
        *(uint4*)((char*)hidT + ((size_t)(b * Ss + q0 + q)) * 4096 + hh * 256 + x * 16) = vv;
    }
}

// ---------------------------------------------------------------------------
// proj5: out[2048][4096] = W @ hidT^T. BM=128, BN=256, BK=64, 512 thr
// (8 waves 2Mx4N, per-wave 64x64). 2 phases per K-tile, 16 MFMA/phase,
// ds_read ∥ stage-issue ∥ MFMA per phase, 3-buffer LDS, vmcnt(6)/K-tile.
// ---------------------------------------------------------------------------
__global__ __launch_bounds__(512, 2) void proj5(const ushort* __restrict__ Wbf,
                                                const ushort* __restrict__ hidT,
                                                float* __restrict__ out) {
    __shared__ __align__(16) char SMEM[147456];
    const int t = threadIdx.x, l = t & 63, w = t >> 6;
    const int kk = l & 15, g = l >> 4;
    const int wr = w >> 2, wc = w & 3;

    const int bid = blockIdx.x;
    const int vid = (bid & 7) * 32 + (bid >> 3);   // 256 blocks, XCD-bijective
    const int o0 = (vid & 15) * 128;               // 16 M-tiles
    const int n0 = (vid >> 4) * 256;               // 16 N-tiles

    f32x4 acc[4][4];
#pragma unroll
    for (int i = 0; i < 4; ++i)
#pragma unroll
        for (int j = 0; j < 4; ++j) acc[i][j] = (f32x4){0.f, 0.f, 0.f, 0.f};

    const int swz = (kk & 7) << 3;

#define P5_STAGE_A(st, ks)                                                      \
    {                                                                           \
        ushort* Ad = (ushort*)SMEM + (st) * 8192;                               \
        _Pragma("unroll")                                                       \
        for (int ii = 0; ii < 2; ++ii) {                                        \
            const int idx = ii * 512 + t;                                       \
            gld16(Wbf + (size_t)(o0 + (idx >> 3)) * 2048 + (ks) * 64 +          \
                      (idx & 7) * 8,                                            \
                  Ad + idx * 8);                                                \
        }                                                                       \
    }
#define P5_STAGE_B(st, ks, p)                                                   \
    {                                                                           \
        ushort* Bd = (ushort*)(SMEM + 49152) + (st) * 16384;                    \
        _Pragma("unroll")                                                       \
        for (int jj = (p) * 2; jj < (p) * 2 + 2; ++jj) {                        \
            const int idx = jj * 512 + t;                                       \
            gld16(hidT + (size_t)(n0 + (idx >> 3)) * 2048 + (ks) * 64 +         \
                      (idx & 7) * 8,                                            \
                  Bd + idx * 8);                                                \
        }                                                                       \
    }
#define P5_READ(dcv)                                                            \
    _Pragma("unroll")                                                           \
    for (int ms = 0; ms < 4; ++ms)                                              \
        af[ms] = *(const bf16x8*)&Ab[(wr * 64 + ms * 16 + kk) * 64 +            \
                                     (((dcv) * 32 + g * 8) ^ swz)];             \
    _Pragma("unroll")                                                           \
    for (int ns = 0; ns < 4; ++ns)                                              \
        bfr[ns] = *(const bf16x8*)&Bb[(wc * 64 + ns * 16 + kk) * 64 +           \
                                      (((dcv) * 32 + g * 8) ^ swz)];
#define P5_MFMA()                                                               \
    __builtin_amdgcn_s_setprio(1);                                              \
    _Pragma("unroll")                                                           \
    for (int ms = 0; ms < 4; ++ms)                                              \
        _Pragma("unroll")                                                       \
        for (int ns = 0; ns < 4; ++ns)                                          \
            acc[ms][ns] = __builtin_amdgcn_mfma_f32_16x16x32_bf16(              \
                af[ms], bfr[ns], acc[ms][ns], 0, 0, 0);                         \
    __builtin_amdgcn_s_setprio(0);

    P5_STAGE_A(0, 0); P5_STAGE_B(0, 0, 0); P5_STAGE_B(0, 0, 1);
    P5_STAGE_A(1, 1); P5_STAGE_B(1, 1, 0); P5_STAGE_B(1, 1, 1);
    asm volatile("s_waitcnt vmcnt(6)" ::: "memory");
    __builtin_amdgcn_s_barrier();

    int ct = 0, st2 = 2;
    for (int tt = 0; tt < 32; ++tt) {
        const ushort* Ab = (const ushort*)SMEM + ct * 8192;
        const ushort* Bb = (const ushort*)(SMEM + 49152) + ct * 16384;
        bf16x8 af[4], bfr[4];

        // ---- phase 0 (dc=0): ds_read 8 ∥ stage A + B-half ----
        P5_READ(0);
        if (tt < 30) { P5_STAGE_A(st2, tt + 2); P5_STAGE_B(st2, tt + 2, 0); }
        __builtin_amdgcn_s_barrier();
        asm volatile("s_waitcnt lgkmcnt(0)" ::: "memory");
        P5_MFMA();
        __builtin_amdgcn_s_barrier();

        // ---- phase 1 (dc=1): ds_read 8 ∥ stage B-half; counted vmcnt ----
        P5_READ(1);
        if (tt < 30) P5_STAGE_B(st2, tt + 2, 1);
        if (tt < 30) { asm volatile("s_waitcnt vmcnt(6)" ::: "memory"); }
        else         { asm volatile("s_waitcnt vmcnt(0)" ::: "memory"); }
        __builtin_amdgcn_s_barrier();
        asm volatile("s_waitcnt lgkmcnt(0)" ::: "memory");
        P5_MFMA();
        __builtin_amdgcn_s_barrier();

        ct = (ct == 2) ? 0 : ct + 1;
        st2 = (st2 == 2) ? 0 : st2 + 1;
    }
#undef P5_STAGE_A
#undef P5_STAGE_B
#undef P5_READ
#undef P5_MFMA

#pragma unroll
    for (int ms = 0; ms < 4; ++ms)
#pragma unroll
        for (int ns = 0; ns < 4; ++ns) {
            const int o = o0 + wr * 64 + ms * 16 + g * 4;
            const int n = n0 + wc * 64 + ns * 16 + kk;
            const int bb = n >> 10, qq = n & 1023;
            float* op = out + ((size_t)(bb * Cc + o)) * Ss + qq;
#pragma unroll
            for (int r = 0; r < 4; ++r) op[(size_t)r * Ss] = acc[ms][ns][r];
        }
}

extern "C" void kernel_launch(void* const* d_in, const int* in_sizes, int n_in,
                              void* d_out, int out_size, void* d_ws, size_t ws_size,
                              hipStream_t stream) {
    const float*    keys    = (const float*)d_in[0];
    const float*    values  = (const float*)d_in[1];
    const float*    queries = (const float*)d_in[2];
    const unsigned* mask    = (const unsigned*)d_in[3];
    const float*    w_out   = (const float*)d_in[4];
    float* out = (float*)d_out;

    char* ws = (char*)d_ws;
    float*  bias = (float*)ws;                              // 16 KB
    ushort* Wbf  = (ushort*)(ws + 16384);                   // 8 MB
    ushort* Kt   = (ushort*)(ws + 16384 + (8u << 20));      // 16 MB
    ushort* Vbf  = (ushort*)(ws + 16384 + (24u << 20));     // 16 MB
    ushort* hidT = (ushort*)(ws + 16384 + (40u << 20));     // 16 MB

    hipLaunchKernelGGL(prep_all3, dim3(7169), dim3(256), 0, stream,
                       w_out, values, keys, mask, Wbf, Vbf, Kt, bias);
    hipLaunchKernelGGL(attn12, dim3(512), dim3(256), 0, stream,
                       queries, Kt, Vbf, bias, hidT);
    hipLaunchKernelGGL(proj5, dim3(256), dim3(512), 0, stream,
                       Wbf, hidT, out);
}

// Round 14
// 116.158 us; speedup vs baseline: 1.6121x; 1.6121x over previous
//
#include <hip/hip_runtime.h>

#define Bq 4
#define Cc 2048
#define Ss 1024
#define Hh 16
#define Dd 128

// 1/sqrt(128) * log2(e): softmax runs in exp2 domain, folded into Q at load
#define QSCALE 0.127517429f

typedef __bf16 bf16x8 __attribute__((ext_vector_type(8)));
typedef float  f32x4  __attribute__((ext_vector_type(4)));
typedef float  f32x16 __attribute__((ext_vector_type(16)));

__device__ __forceinline__ ushort f2bf(float f) {
    uint u = __float_as_uint(f);
    u += 0x7FFFu + ((u >> 16) & 1u);   // RNE
    return (ushort)(u >> 16);
}
__device__ __forceinline__ uint pack2bf(float a, float b) {
    return (uint)f2bf(a) | ((uint)f2bf(b) << 16);
}
__device__ __forceinline__ void gld16(const void* g, void* l) {
    __builtin_amdgcn_global_load_lds(
        (const __attribute__((address_space(1))) unsigned int*)g,
        (__attribute__((address_space(3))) unsigned int*)l, 16, 0, 0);
}

// ---------------------------------------------------------------------------
// prep_all3: one kernel, four block-ranges (Q handled inside attn).
//   [0,2048)     W fp32[2048][2048] -> bf16, intra-128B XOR swizzle (row&7)
//   [2048,6144)  V fp32 -> bf16, k-permuted for 32x32 swapped-QK P layout
//                (swap bits 2<->3 of k within each 16-block) + row-XOR swizzle
//   [6144,7168)  K transpose [d][S] -> [S][128] bf16, XOR swizzle by k&7
//   [7168]       mask -> bias (0/-1e30), runtime dtype detection
// ---------------------------------------------------------------------------
__global__ __launch_bounds__(256) void prep_all3(const float* __restrict__ w,
                                                 const float* __restrict__ v,
                                                 const float* __restrict__ keys,
                                                 const unsigned* __restrict__ mask,
                                                 ushort* __restrict__ wb,
                                                 ushort* __restrict__ vb,
                                                 ushort* __restrict__ Kt,
                                                 float* __restrict__ bias) {
    __shared__ __align__(16) float T[128][65];
    const int t = threadIdx.x;
    const int blk = blockIdx.x;

    if (blk < 2048) {
        // ---- W convert+swizzle ----
        const size_t e = ((size_t)blk * 256 + t) * 8;
        const int row = (int)(e >> 11), col = (int)(e & 2047);
        const int colS = (col & ~63) | ((col & 63) ^ ((row & 7) << 3));
        float4 v0 = *(const float4*)&w[e];
        float4 v1 = *(const float4*)&w[e + 4];
        uint4 o;
        o.x = pack2bf(v0.x, v0.y); o.y = pack2bf(v0.z, v0.w);
        o.z = pack2bf(v1.x, v1.y); o.w = pack2bf(v1.z, v1.w);
        *(uint4*)&wb[(size_t)row * 2048 + colS] = o;
    } else if (blk < 6144) {
        // ---- V convert + k-permute (bit2<->bit3 swap) + row-XOR swizzle ----
        const int tid = (blk - 2048) * 256 + t;    // 0 .. 1M-1
        const int row = tid >> 7;                   // 0..8191
        const int cp = tid & 127;
        const int blk64 = (cp >> 3) * 64;
        const int j0 = cp & 7;                      // 8-k'' output group
        const int base = (j0 >> 1) * 16 + (j0 & 1) * 4;
        const float* src = v + (size_t)row * 1024 + blk64 + base;
        float4 A = *(const float4*)src;            // k'' j=0..3  <- k base+0..3
        float4 B = *(const float4*)(src + 8);      // k'' j=4..7  <- k base+8..11
        uint4 o;
        o.x = pack2bf(A.x, A.y); o.y = pack2bf(A.z, A.w);
        o.z = pack2bf(B.x, B.y); o.w = pack2bf(B.z, B.w);
        *(uint4*)&vb[(size_t)row * 1024 + blk64 + ((j0 * 8) ^ ((row & 7) << 3))] = o;
    } else if (blk < 7168) {
        // ---- K transpose+convert+swizzle ----
        const int b2 = blk - 6144;
        const int s0 = (b2 & 15) * 64;
        const int bh = b2 >> 4;
        const float* src = keys + (size_t)bh * 128 * 1024;
#pragma unroll
        for (int p = 0; p < 8; ++p) {
            const int d = p * 16 + (t >> 4);
            float4 v4 = *(const float4*)&src[(size_t)d * 1024 + s0 + (t & 15) * 4];
            T[d][(t & 15) * 4 + 0] = v4.x;
            T[d][(t & 15) * 4 + 1] = v4.y;
            T[d][(t & 15) * 4 + 2] = v4.z;
            T[d][(t & 15) * 4 + 3] = v4.w;
        }
        __syncthreads();
#pragma unroll
        for (int p = 0; p < 4; ++p) {
            const int k = p * 16 + (t >> 4);
            const int x = t & 15;
            uint4 o;
            o.x = pack2bf(T[x * 8 + 0][k], T[x * 8 + 1][k]);
            o.y = pack2bf(T[x * 8 + 2][k], T[x * 8 + 3][k]);
            o.z = pack2bf(T[x * 8 + 4][k], T[x * 8 + 5][k]);
            o.w = pack2bf(T[x * 8 + 6][k], T[x * 8 + 7][k]);
            const size_t rowbyte = ((size_t)bh * 1024 + s0 + k) * 256;
            const int boff = (x * 16) ^ ((k & 7) << 4);
            *(uint4*)((char*)Kt + rowbyte + boff) = o;
        }
    } else {
        // ---- mask -> bias ----
        __shared__ int f01, ff;
        if (t == 0) { f01 = 0; ff = 0; }
        __syncthreads();
        int a = 0, c = 0;
        for (int i = t; i < 1024; i += 256) {
            unsigned vv = mask[i];
            if (vv != 0u && vv != 1u) a = 1;
            if (vv != 0u && vv != 0x3F800000u) c = 1;
        }
        if (a) atomicOr(&f01, 1);
        if (c) atomicOr(&ff, 1);
        __syncthreads();
        const int mode = f01 ? (ff ? 1 : 2) : 0;
        const int* mi = (const int*)mask;
        const unsigned char* mb = (const unsigned char*)mask;
        const float* mf = (const float*)mask;
        for (int i = t; i < Bq * Ss; i += 256) {
            bool on;
            if (mode == 0)      on = (mi[i] != 0);
            else if (mode == 1) on = (mb[i] != 0);
            else                on = (mf[i] != 0.0f);
            bias[i] = on ? 0.0f : -1e30f;
        }
    }
}

// ---------------------------------------------------------------------------
// MFMA flash attention v13 — 32x32x16 fragments. 256 blocks x 512 thr
// (8 waves); q-tile 256 (wave owns 32 q, lane owns ONE q = l&31); KVBLK 64
// triple-buffered, counted vmcnt(4). Swapped-QK (D[k][q]), P stays in
// CONTIGUOUS regs (pb[m] = exp2(sc[8m..8m+7])), bias as MFMA C-init,
// fixed-max softmax, in-kernel Q prologue. Half the MFMA instructions of
// the 16x16 version at the higher 32x32 rate.
// ---------------------------------------------------------------------------
__global__ __launch_bounds__(512) void attn13(const float* __restrict__ queries,
                                              const ushort* __restrict__ Kt,
                                              const ushort* __restrict__ Vbf,
                                              const float* __restrict__ bias,
                                              ushort* __restrict__ hidT) {
    __shared__ __align__(16) char SMEM[102400];
    // K: 3 x [64][128] (16 KB) at 0; V: 3 x [128][64] at 49152; bias at 98304
    // prologue reuses [0,64K) as Q fp32 stage [64 d][256 q]
    float* biasS = (float*)(SMEM + 98304);

    const int t = threadIdx.x, l = t & 63, w = t >> 6;   // w = 0..7
    const int l31 = l & 31, hi = l >> 5;
    const int swz = (l31 & 7) << 4;     // byte-XOR for KT/Vs fragment reads

    const int bid = blockIdx.x;
    const int vid = (bid & 7) * 32 + (bid >> 3);   // XCD-affine (256 blocks)
    const int bh = vid >> 2, qt = vid & 3;
    const int b = bh >> 4, hh = bh & 15;
    const int q0 = qt * 256;
    const size_t bhbase = (size_t)bh * 1024;

    for (int i = t; i < Ss; i += 512) biasS[i] = bias[b * Ss + i];

    // ---- Q prologue: stage [64 d][256 q] fp32 per half, extract B-frags ----
    // frag dm (0..7): lane holds Q[d = dm*16 + hi*8 + j][q = w*32 + l31]
    bf16x8 qf[8];
    {
        const float* Qg = queries + (size_t)(b * Cc + hh * Dd) * Ss;
        float* Qstg = (float*)SMEM;
        const int q = w * 32 + l31;
#pragma unroll
        for (int half = 0; half < 2; ++half) {
#pragma unroll
            for (int it = 0; it < 8; ++it) {
                const int row = it * 8 + w;         // wave-uniform dest row
                gld16(Qg + (size_t)(half * 64 + row) * 1024 + q0 + l * 4,
                      (char*)Qstg + row * 1024);
            }
            __syncthreads();                        // drains vmcnt + barrier
#pragma unroll
            for (int dmL = 0; dmL < 4; ++dmL) {
                float f[8];
#pragma unroll
                for (int j = 0; j < 8; ++j)
                    f[j] = Qstg[(dmL * 16 + hi * 8 + j) * 256 + q];
                uint4 u;
                u.x = pack2bf(f[0] * QSCALE, f[1] * QSCALE);
                u.y = pack2bf(f[2] * QSCALE, f[3] * QSCALE);
                u.z = pack2bf(f[4] * QSCALE, f[5] * QSCALE);
                u.w = pack2bf(f[6] * QSCALE, f[7] * QSCALE);
                qf[half * 4 + dmL] = *(bf16x8*)&u;
            }
            __syncthreads();   // extraction done before overwrite
        }
    }

    float lrun = 0.0f;
    f32x16 hacc[4];
#pragma unroll
    for (int ds = 0; ds < 4; ++ds)
#pragma unroll
        for (int r = 0; r < 16; ++r) hacc[ds][r] = 0.0f;

#define ATTN_STAGE(bufi, cki)                                                   \
    {                                                                           \
        const int k0n = (cki) * 64;                                             \
        ushort* Kd = (ushort*)SMEM + (bufi) * 8192;                             \
        ushort* Vd = (ushort*)(SMEM + 49152) + (bufi) * 8192;                   \
        _Pragma("unroll")                                                       \
        for (int ii = 0; ii < 4; ++ii) {                                        \
            const int inst = ii * 8 + w;                                        \
            if (inst < 16) {                                                    \
                gld16(Kt + (bhbase + k0n + inst * 4 + (l >> 4)) * 128 +         \
                          (l & 15) * 8,                                         \
                      Kd + inst * 512);                                         \
            } else {                                                            \
                const int i2 = inst - 16;                                       \
                gld16(Vbf + ((size_t)bh * 128 + i2 * 8 + (l >> 3)) * 1024 +     \
                          k0n + (l & 7) * 8,                                    \
                      Vd + i2 * 512);                                           \
            }                                                                   \
        }                                                                       \
    }

    // QK subtile ks: D[k 32][q 32] = sum_d K-frag x Q-frag; C-init = bias.
#define QK_SUB(ks, scv)                                                          \
    {                                                                            \
        f32x16 a;                                                                \
        _Pragma("unroll")                                                        \
        for (int qd = 0; qd < 4; ++qd) {                                         \
            f32x4 cv = *(const f32x4*)&biasS[k0 + (ks) * 32 + qd * 8 + hi * 4];  \
            a[qd * 4 + 0] = cv[0]; a[qd * 4 + 1] = cv[1];                        \
            a[qd * 4 + 2] = cv[2]; a[qd * 4 + 3] = cv[3];                        \
        }                                                                        \
        const char* kr = KTb + ((ks) * 32 + l31) * 256;                          \
        __builtin_amdgcn_s_setprio(1);                                           \
        _Pragma("unroll")                                                        \
        for (int dm = 0; dm < 8; ++dm) {                                         \
            bf16x8 kf = *(const bf16x8*)(kr + ((dm * 32 + hi * 16) ^ swz));      \
            a = __builtin_amdgcn_mfma_f32_32x32x16_bf16(kf, qf[dm], a, 0, 0, 0); \
        }                                                                        \
        __builtin_amdgcn_s_setprio(0);                                           \
        scv = a;                                                                 \
    }

    // SM subtile: pb[m][j] = exp2(sc[8m+j]) -- contiguous reg runs.
#define SM_SUB(scv, p0, p1)                                                      \
    {                                                                            \
        float s = 0.0f;                                                          \
        _Pragma("unroll")                                                        \
        for (int j = 0; j < 8; ++j) {                                            \
            float e = exp2f(scv[j]);  s += e;  p0[j] = (__bf16)e;                \
        }                                                                        \
        _Pragma("unroll")                                                        \
        for (int j = 0; j < 8; ++j) {                                            \
            float e = exp2f(scv[8 + j]);  s += e;  p1[j] = (__bf16)e;            \
        }                                                                        \
        lrun += s;                                                               \
    }

    // PV windows of subtile ks: hacc[dsub] += V-frag x P-frag
#define PV_SUB(ks, p0, p1)                                                       \
    {                                                                            \
        __builtin_amdgcn_s_setprio(1);                                           \
        _Pragma("unroll")                                                        \
        for (int m = 0; m < 2; ++m) {                                            \
            const int ko = (ks) * 64 + m * 32 + hi * 16;                         \
            _Pragma("unroll")                                                    \
            for (int dsub = 0; dsub < 4; ++dsub) {                               \
                const int d = dsub * 32 + l31;                                   \
                bf16x8 vf = *(const bf16x8*)(Vsb + d * 128 + (ko ^ swz));        \
                hacc[dsub] = __builtin_amdgcn_mfma_f32_32x32x16_bf16(            \
                    vf, (m == 0 ? p0 : p1), hacc[dsub], 0, 0, 0);                \
            }                                                                    \
        }                                                                        \
        __builtin_amdgcn_s_setprio(0);                                           \
    }

#define ATTN_COMPUTE(bi, ck)                                                     \
    {                                                                            \
        const int k0 = (ck) * 64;                                                \
        const char* KTb = SMEM + (bi) * 16384;                                   \
        const char* Vsb = SMEM + 49152 + (bi) * 16384;                           \
        f32x16 sc0, sc1;                                                         \
        bf16x8 p00, p01, p10, p11;                                               \
        QK_SUB(0, sc0);                                                          \
        QK_SUB(1, sc1);                                                          \
        SM_SUB(sc0, p00, p01);                                                   \
        PV_SUB(0, p00, p01);                                                     \
        SM_SUB(sc1, p10, p11);                                                   \
        PV_SUB(1, p10, p11);                                                     \
    }

    // prologue: 2 tiles in flight; wait for tile 0 only (counted)
    ATTN_STAGE(0, 0);
    ATTN_STAGE(1, 1);
    asm volatile("s_waitcnt vmcnt(4)" ::: "memory");
    __builtin_amdgcn_s_barrier();

    int cb = 0, sb = 2;
    for (int ck = 0; ck < 14; ++ck) {
        ATTN_STAGE(sb, ck + 2);
        ATTN_COMPUTE(cb, ck);
        asm volatile("s_waitcnt vmcnt(4)" ::: "memory");  // next tile landed
        __builtin_amdgcn_s_barrier();
        cb = (cb == 2) ? 0 : cb + 1;
        sb = (sb == 2) ? 0 : sb + 1;
    }
    ATTN_COMPUTE(cb, 14);
    asm volatile("s_waitcnt vmcnt(0)" ::: "memory");
    __builtin_amdgcn_s_barrier();
    cb = (cb == 2) ? 0 : cb + 1;
    ATTN_COMPUTE(cb, 15);
#undef ATTN_STAGE
#undef ATTN_COMPUTE
#undef QK_SUB
#undef SM_SUB
#undef PV_SUB

    // l: lane + hi-complement lane hold the two halves of each chunk's k
    const float linv = 1.0f / (lrun + __shfl_xor(lrun, 32));

    __syncthreads();   // done with K/V buffers; reuse as [256 q][128 d] stage
    {
        ushort* hs = (ushort*)SMEM;
        const int row = w * 32 + l31;
        const int rsw = (row & 7) << 4;
#pragma unroll
        for (int dsub = 0; dsub < 4; ++dsub)
#pragma unroll
            for (int qd = 0; qd < 4; ++qd) {
                // regs qd*4+i -> d = dsub*32 + qd*8 + hi*4 + i
                uint2 pk;
                pk.x = pack2bf(hacc[dsub][qd * 4 + 0] * linv,
                               hacc[dsub][qd * 4 + 1] * linv);
                pk.y = pack2bf(hacc[dsub][qd * 4 + 2] * linv,
                               hacc[dsub][qd * 4 + 3] * linv);
                const int off = row * 256 + ((dsub * 64 + qd * 16 + hi * 8) ^ rsw);
                *(uint2*)((char*)hs + off) = pk;
            }
    }
    __syncthreads();

    const char* hsb = (const char*)SMEM;
#pragma unroll
    for (int it = 0; it < 8; ++it) {
        const int idx = it * 512 + t;                  // 0..4095
        const int q = idx >> 4, x = idx & 15;
        uint4 vv = *(const uint4*)(hsb + q * 256 + x * 16);
        *(uint4*)((char*)hidT + ((size_t)(b * Ss + q0 + q)) * 4096 + hh * 256 + x * 16) = vv;
    }
}

// ---------------------------------------------------------------------------
// proj5: out[2048][4096] = W @ hidT^T. BM=128, BN=256, BK=64, 512 thr
// (8 waves 2Mx4N, per-wave 64x64). 2 phases per K-tile, 16 MFMA/phase,
// ds_read ∥ stage-issue ∥ MFMA per phase, 3-buffer LDS, vmcnt(6)/K-tile.
// ---------------------------------------------------------------------------
__global__ __launch_bounds__(512, 2) void proj5(const ushort* __restrict__ Wbf,
                                                const ushort* __restrict__ hidT,
                                                float* __restrict__ out) {
    __shared__ __align__(16) char SMEM[147456];
    const int t = threadIdx.x, l = t & 63, w = t >> 6;
    const int kk = l & 15, g = l >> 4;
    const int wr = w >> 2, wc = w & 3;

    const int bid = blockIdx.x;
    const int vid = (bid & 7) * 32 + (bid >> 3);   // 256 blocks, XCD-bijective
    const int o0 = (vid & 15) * 128;               // 16 M-tiles
    const int n0 = (vid >> 4) * 256;               // 16 N-tiles

    f32x4 acc[4][4];
#pragma unroll
    for (int i = 0; i < 4; ++i)
#pragma unroll
        for (int j = 0; j < 4; ++j) acc[i][j] = (f32x4){0.f, 0.f, 0.f, 0.f};

    const int swz = (kk & 7) << 3;

#define P5_STAGE_A(st, ks)                                                      \
    {                                                                           \
        ushort* Ad = (ushort*)SMEM + (st) * 8192;                               \
        _Pragma("unroll")                                                       \
        for (int ii = 0; ii < 2; ++ii) {                                        \
            const int idx = ii * 512 + t;                                       \
            gld16(Wbf + (size_t)(o0 + (idx >> 3)) * 2048 + (ks) * 64 +          \
                      (idx & 7) * 8,                                            \
                  Ad + idx * 8);                                                \
        }                                                                       \
    }
#define P5_STAGE_B(st, ks, p)                                                   \
    {                                                                           \
        ushort* Bd = (ushort*)(SMEM + 49152) + (st) * 16384;                    \
        _Pragma("unroll")                                                       \
        for (int jj = (p) * 2; jj < (p) * 2 + 2; ++jj) {                        \
            const int idx = jj * 512 + t;                                       \
            gld16(hidT + (size_t)(n0 + (idx >> 3)) * 2048 + (ks) * 64 +         \
                      (idx & 7) * 8,                                            \
                  Bd + idx * 8);                                                \
        }                                                                       \
    }
#define P5_READ(dcv)                                                            \
    _Pragma("unroll")                                                           \
    for (int ms = 0; ms < 4; ++ms)                                              \
        af[ms] = *(const bf16x8*)&Ab[(wr * 64 + ms * 16 + kk) * 64 +            \
                                     (((dcv) * 32 + g * 8) ^ swz)];             \
    _Pragma("unroll")                                                           \
    for (int ns = 0; ns < 4; ++ns)                                              \
        bfr[ns] = *(const bf16x8*)&Bb[(wc * 64 + ns * 16 + kk) * 64 +           \
                                      (((dcv) * 32 + g * 8) ^ swz)];
#define P5_MFMA()                                                               \
    __builtin_amdgcn_s_setprio(1);                                              \
    _Pragma("unroll")                                                           \
    for (int ms = 0; ms < 4; ++ms)                                              \
        _Pragma("unroll")                                                       \
        for (int ns = 0; ns < 4; ++ns)                                          \
            acc[ms][ns] = __builtin_amdgcn_mfma_f32_16x16x32_bf16(              \
                af[ms], bfr[ns], acc[ms][ns], 0, 0, 0);                         \
    __builtin_amdgcn_s_setprio(0);

    P5_STAGE_A(0, 0); P5_STAGE_B(0, 0, 0); P5_STAGE_B(0, 0, 1);
    P5_STAGE_A(1, 1); P5_STAGE_B(1, 1, 0); P5_STAGE_B(1, 1, 1);
    asm volatile("s_waitcnt vmcnt(6)" ::: "memory");
    __builtin_amdgcn_s_barrier();

    int ct = 0, st2 = 2;
    for (int tt = 0; tt < 32; ++tt) {
        const ushort* Ab = (const ushort*)SMEM + ct * 8192;
        const ushort* Bb = (const ushort*)(SMEM + 49152) + ct * 16384;
        bf16x8 af[4], bfr[4];

        // ---- phase 0 (dc=0): ds_read 8 ∥ stage A + B-half ----
        P5_READ(0);
        if (tt < 30) { P5_STAGE_A(st2, tt + 2); P5_STAGE_B(st2, tt + 2, 0); }
        __builtin_amdgcn_s_barrier();
        asm volatile("s_waitcnt lgkmcnt(0)" ::: "memory");
        P5_MFMA();
        __builtin_amdgcn_s_barrier();

        // ---- phase 1 (dc=1): ds_read 8 ∥ stage B-half; counted vmcnt ----
        P5_READ(1);
        if (tt < 30) P5_STAGE_B(st2, tt + 2, 1);
        if (tt < 30) { asm volatile("s_waitcnt vmcnt(6)" ::: "memory"); }
        else         { asm volatile("s_waitcnt vmcnt(0)" ::: "memory"); }
        __builtin_amdgcn_s_barrier();
        asm volatile("s_waitcnt lgkmcnt(0)" ::: "memory");
        P5_MFMA();
        __builtin_amdgcn_s_barrier();

        ct = (ct == 2) ? 0 : ct + 1;
        st2 = (st2 == 2) ? 0 : st2 + 1;
    }
#undef P5_STAGE_A
#undef P5_STAGE_B
#undef P5_READ
#undef P5_MFMA

#pragma unroll
    for (int ms = 0; ms < 4; ++ms)
#pragma unroll
        for (int ns = 0; ns < 4; ++ns) {
            const int o = o0 + wr * 64 + ms * 16 + g * 4;
            const int n = n0 + wc * 64 + ns * 16 + kk;
            const int bb = n >> 10, qq = n & 1023;
            float* op = out + ((size_t)(bb * Cc + o)) * Ss + qq;
#pragma unroll
            for (int r = 0; r < 4; ++r) op[(size_t)r * Ss] = acc[ms][ns][r];
        }
}

extern "C" void kernel_launch(void* const* d_in, const int* in_sizes, int n_in,
                              void* d_out, int out_size, void* d_ws, size_t ws_size,
                              hipStream_t stream) {
    const float*    keys    = (const float*)d_in[0];
    const float*    values  = (const float*)d_in[1];
    const float*    queries = (const float*)d_in[2];
    const unsigned* mask    = (const unsigned*)d_in[3];
    const float*    w_out   = (const float*)d_in[4];
    float* out = (float*)d_out;

    char* ws = (char*)d_ws;
    float*  bias = (float*)ws;                              // 16 KB
    ushort* Wbf  = (ushort*)(ws + 16384);                   // 8 MB
    ushort* Kt   = (ushort*)(ws + 16384 + (8u << 20));      // 16 MB
    ushort* Vbf  = (ushort*)(ws + 16384 + (24u << 20));     // 16 MB
    ushort* hidT = (ushort*)(ws + 16384 + (40u << 20));     // 16 MB

    hipLaunchKernelGGL(prep_all3, dim3(7169), dim3(256), 0, stream,
                       w_out, values, keys, mask, Wbf, Vbf, Kt, bias);
    hipLaunchKernelGGL(attn13, dim3(256), dim3(512), 0, stream,
                       queries, Kt, Vbf, bias, hidT);
    hipLaunchKernelGGL(proj5, dim3(256), dim3(512), 0, stream,
                       Wbf, hidT, out);
}